// Round 5
// baseline (232.049 us; speedup 1.0000x reference)
//
#include <hip/hip_runtime.h>

#define N_NODES 50000
#define N_EDGES 800000
#define IN_F 256
#define OUT_F 128

#define CHUNKS 128
#define EPC (N_EDGES / CHUNKS)   // 6250 edges per chunk
#define RANGES 2
#define BPR 25000                // bins per range
#define BPRW (BPR / 2)           // packed u32 words (2 x u16 bins)
#define NGB 196                  // node-group blocks (256 nodes each)
#define CG 8                     // chunk groups
#define CPG (CHUNKS / CG)        // 16 chunks per group

typedef __attribute__((ext_vector_type(8))) short short8;
typedef __attribute__((ext_vector_type(4))) float float4_t;

// float -> bf16 round-to-nearest-even
__device__ __forceinline__ short f2bf(float f) {
  unsigned u = __builtin_bit_cast(unsigned, f);
  u = u + 0x7FFFu + ((u >> 16) & 1u);
  return (short)(u >> 16);
}

// ---- histogram + per-edge rank (LDS-privatized) + fused wprep ----
// blocks 0..511: b>>8 = side (0:dst, 1:src), (b>>1)&127 = chunk, b&1 = range
// blocks 512..513: W -> bf16 MFMA B-fragment layout
__global__ __launch_bounds__(256) void hist_kernel(const int* __restrict__ src,
                                                   const int* __restrict__ dst,
                                                   unsigned short* __restrict__ pdst,
                                                   unsigned short* __restrict__ psrc,
                                                   unsigned short* __restrict__ rank16,
                                                   const float* __restrict__ W,
                                                   short* __restrict__ Wf) {
  __shared__ unsigned bins[BPRW];
  int b = blockIdx.x;
  int t = threadIdx.x;
  if (b >= 512) {
    int bb = b - 512;
#pragma unroll
    for (int i = 0; i < 64; ++i) {
      int idx = bb * 16384 + i * 256 + t;
      int k = idx >> 7, n = idx & 127;
      int s = k >> 5, q = (k >> 3) & 3, j = k & 7;
      int tt = n >> 4, m = n & 15;
      Wf[(((s * 8 + tt) * 16 + m) * 32) + q * 8 + j] = f2bf(W[idx]);
    }
    return;
  }
  int h = b >> 8;
  int c = (b >> 1) & 127;
  int r = b & 1;
  int rbase = r * BPR;
  for (int j = t; j < BPRW; j += 256) bins[j] = 0;
  __syncthreads();
  const int* key = h ? src : dst;
  int e0 = c * EPC;
  for (int i = t; i < EPC; i += 256) {
    int v = key[e0 + i] - rbase;
    if ((unsigned)v < (unsigned)BPR) {
      unsigned sh = (v & 1) * 16;
      unsigned old = atomicAdd(&bins[v >> 1], 1u << sh);
      if (!h) rank16[e0 + i] = (unsigned short)((old >> sh) & 0xFFFFu);
    }
  }
  __syncthreads();
  unsigned* p32 = (unsigned*)((h ? psrc : pdst) + (size_t)c * N_NODES + rbase);
  for (int j = t; j < BPRW; j += 256) p32[j] = bins[j];
}

// grid (NGB, 2): side 0 -> cnt, cnt_cg, blockSums; side 1 -> norm
__global__ __launch_bounds__(256) void reduce_kernel(const unsigned short* __restrict__ pdst,
                                                     const unsigned short* __restrict__ psrc,
                                                     int* __restrict__ cnt,
                                                     unsigned short* __restrict__ cnt_cg,
                                                     int* __restrict__ blockSums,
                                                     float* __restrict__ norm) {
  int g = blockIdx.x, side = blockIdx.y;
  int t = threadIdx.x;
  int v = g * 256 + t;
  bool ok = v < N_NODES;
  if (side == 0) {
    int s = 0;
#pragma unroll
    for (int cg = 0; cg < CG; ++cg) {
      int sub = 0;
#pragma unroll
      for (int c = cg * CPG; c < cg * CPG + CPG; ++c)
        sub += ok ? (int)pdst[(size_t)c * N_NODES + v] : 0;
      if (ok) cnt_cg[(size_t)cg * N_NODES + v] = (unsigned short)sub;
      s += sub;
    }
    if (ok) cnt[v] = s;
    // block reduce -> blockSums[g]
    int l = t & 63, w = t >> 6;
    for (int off = 32; off > 0; off >>= 1) s += __shfl_down(s, off);
    __shared__ int wp[4];
    if (l == 0) wp[w] = s;
    __syncthreads();
    if (t == 0) blockSums[g] = wp[0] + wp[1] + wp[2] + wp[3];
  } else {
    int gsum = 0;
#pragma unroll
    for (int c = 0; c < CHUNKS; ++c)
      gsum += ok ? (int)psrc[(size_t)c * N_NODES + v] : 0;
    if (ok) norm[v] = 1.0f / (float)(gsum > 1 ? gsum : 1);
  }
}

// grid NGB: each block scans all block sums in LDS, then block-local scan of cnt -> row_off
__global__ __launch_bounds__(256) void csr_kernel(const int* __restrict__ cnt,
                                                  const int* __restrict__ blockSums,
                                                  int* __restrict__ row_off) {
  __shared__ int sc[256];
  int t = threadIdx.x, g = blockIdx.x;
  sc[t] = (t < NGB) ? blockSums[t] : 0;
  __syncthreads();
  for (int off = 1; off < 256; off <<= 1) {
    int nv = (t >= off) ? sc[t - off] : 0;
    __syncthreads();
    sc[t] += nv;
    __syncthreads();
  }
  int myBase = sc[g] - blockSums[g];  // exclusive prefix for this block
  int v = g * 256 + t;
  int cv = (v < N_NODES) ? cnt[v] : 0;
  int l = t & 63, w = t >> 6;
  int x = cv;
  for (int off = 1; off < 64; off <<= 1) {
    int y = __shfl_up(x, off);
    if (l >= off) x += y;
  }
  __shared__ int wp[4];
  if (l == 63) wp[w] = x;
  __syncthreads();
  int add = 0;
  for (int i = 0; i < w; ++i) add += wp[i];
  int P = myBase + add + x - cv;  // exclusive global prefix
  if (v < N_NODES) {
    row_off[v] = P;
    if (v == N_NODES - 1) row_off[N_NODES] = P + cv;
  }
}

// grid (NGB, CG): delta[c][v] = sum of pdst[c'<c][v] within-node chunk prefix (u16)
__global__ __launch_bounds__(256) void offsets_kernel(const unsigned short* __restrict__ pdst,
                                                      const unsigned short* __restrict__ cnt_cg,
                                                      unsigned short* __restrict__ delta) {
  int g = blockIdx.x, cg = blockIdx.y;
  int v = g * 256 + threadIdx.x;
  if (v >= N_NODES) return;
  int run = 0;
  for (int p = 0; p < cg; ++p) run += cnt_cg[(size_t)p * N_NODES + v];
  int c0 = cg * CPG;
#pragma unroll
  for (int c = c0; c < c0 + CPG; ++c) {
    delta[(size_t)c * N_NODES + v] = (unsigned short)run;
    run += pdst[(size_t)c * N_NODES + v];
  }
}

// stateless streaming scatter: pos = row_off[dst] + delta[chunk][dst] + rank16[e]
__global__ __launch_bounds__(256) void scatter_kernel(const int* __restrict__ src,
                                                      const int* __restrict__ dst,
                                                      const int* __restrict__ row_off,
                                                      const unsigned short* __restrict__ delta,
                                                      const unsigned short* __restrict__ rank16,
                                                      int* __restrict__ eidx) {
  int tid = blockIdx.x * 256 + threadIdx.x;
  int e = tid * 4;
  if (e >= N_EDGES) return;
  int4 d4 = *(const int4*)(dst + e);
  int4 s4 = *(const int4*)(src + e);
  uint2 rr = *(const uint2*)(rank16 + e);
  int dd[4] = {d4.x, d4.y, d4.z, d4.w};
  int ss[4] = {s4.x, s4.y, s4.z, s4.w};
  unsigned rk[4] = {rr.x & 0xFFFFu, rr.x >> 16, rr.y & 0xFFFFu, rr.y >> 16};
#pragma unroll
  for (int k = 0; k < 4; ++k) {
    int c = (e + k) / EPC;
    int d = dd[k];
    int pos = row_off[d] + (int)delta[(size_t)c * N_NODES + d] + (int)rk[k];
    eidx[pos] = ss[k];
  }
}

// h = (feat @ W) * norm[row], stored as bf16. No LDS.
__global__ __launch_bounds__(256) void gemm_kernel(const float* __restrict__ feat,
                                                   const short* __restrict__ Wf,
                                                   const float* __restrict__ norm,
                                                   unsigned short* __restrict__ h) {
  int tid = threadIdx.x;
  int w = tid >> 6, l = tid & 63;
  int m = l & 15, q = l >> 4;
  long base = (long)blockIdx.x * 128 + w * 32;

  float4_t acc[2][8];
#pragma unroll
  for (int r = 0; r < 2; ++r)
#pragma unroll
    for (int t = 0; t < 8; ++t) acc[r][t] = (float4_t)(0.0f);

  long row0 = base + m;
  long row1 = base + 16 + m;
  long r0c = row0 < N_NODES - 1 ? row0 : N_NODES - 1;
  long r1c = row1 < N_NODES - 1 ? row1 : N_NODES - 1;
  const float* a0p = feat + (size_t)r0c * IN_F;
  const float* a1p = feat + (size_t)r1c * IN_F;
  const short8* bb = (const short8*)Wf;

#pragma unroll
  for (int s = 0; s < 8; ++s) {
    int k0 = s * 32 + q * 8;
    float4_t av0a = *(const float4_t*)(a0p + k0);
    float4_t av0b = *(const float4_t*)(a0p + k0 + 4);
    float4_t av1a = *(const float4_t*)(a1p + k0);
    float4_t av1b = *(const float4_t*)(a1p + k0 + 4);
    short8 fa0, fa1;
#pragma unroll
    for (int i = 0; i < 4; ++i) {
      fa0[i] = f2bf(av0a[i]);
      fa0[i + 4] = f2bf(av0b[i]);
      fa1[i] = f2bf(av1a[i]);
      fa1[i + 4] = f2bf(av1b[i]);
    }
#pragma unroll
    for (int t = 0; t < 8; ++t) {
      short8 fb = bb[((s * 8 + t) * 16 + m) * 4 + q];
      acc[0][t] = __builtin_amdgcn_mfma_f32_16x16x32_bf16(fa0, fb, acc[0][t], 0, 0, 0);
      acc[1][t] = __builtin_amdgcn_mfma_f32_16x16x32_bf16(fa1, fb, acc[1][t], 0, 0, 0);
    }
  }

  // C/D layout: col = lane&15 (=m), row = q*4 + i
#pragma unroll
  for (int r = 0; r < 2; ++r) {
#pragma unroll
    for (int i = 0; i < 4; ++i) {
      long row = base + r * 16 + q * 4 + i;
      if (row < N_NODES) {
        float nm = norm[row];
        size_t ho = (size_t)row * OUT_F;
#pragma unroll
        for (int t = 0; t < 8; ++t) {
          h[ho + t * 16 + m] = (unsigned short)f2bf(acc[r][t][i] * nm);
        }
      }
    }
  }
}

// One wave per dst node. Lane covers 2 columns (one uint = 2 bf16 of h row).
__global__ __launch_bounds__(256) void agg_kernel(const unsigned short* __restrict__ h,
                                                  const int* __restrict__ row_off,
                                                  const int* __restrict__ eidx,
                                                  const float* __restrict__ bias,
                                                  float* __restrict__ out) {
  int w = threadIdx.x >> 6, l = threadIdx.x & 63;
  int d = blockIdx.x * 4 + w;  // grid 12500 -> exactly 50000
  int rs = row_off[d], re = row_off[d + 1];
  const unsigned* __restrict__ hu = (const unsigned*)h;  // 64 uints per row
  float a0 = 0.0f, a1 = 0.0f;
  for (int bse = rs; bse < re; bse += 64) {
    int n = re - bse; if (n > 64) n = 64;
    int e = (l < n) ? eidx[bse + l] : 0;
    int j = 0;
    for (; j + 4 <= n; j += 4) {
      int s0 = __shfl(e, j);
      int s1 = __shfl(e, j + 1);
      int s2 = __shfl(e, j + 2);
      int s3 = __shfl(e, j + 3);
      unsigned v0 = hu[(size_t)s0 * 64 + l];
      unsigned v1 = hu[(size_t)s1 * 64 + l];
      unsigned v2 = hu[(size_t)s2 * 64 + l];
      unsigned v3 = hu[(size_t)s3 * 64 + l];
      a0 += __builtin_bit_cast(float, v0 << 16);
      a1 += __builtin_bit_cast(float, v0 & 0xFFFF0000u);
      a0 += __builtin_bit_cast(float, v1 << 16);
      a1 += __builtin_bit_cast(float, v1 & 0xFFFF0000u);
      a0 += __builtin_bit_cast(float, v2 << 16);
      a1 += __builtin_bit_cast(float, v2 & 0xFFFF0000u);
      a0 += __builtin_bit_cast(float, v3 << 16);
      a1 += __builtin_bit_cast(float, v3 & 0xFFFF0000u);
    }
    for (; j < n; ++j) {
      int s0 = __shfl(e, j);
      unsigned v0 = hu[(size_t)s0 * 64 + l];
      a0 += __builtin_bit_cast(float, v0 << 16);
      a1 += __builtin_bit_cast(float, v0 & 0xFFFF0000u);
    }
  }
  float2 b = ((const float2*)bias)[l];
  float2 o;
  o.x = a0 + b.x;
  o.y = a1 + b.y;
  ((float2*)(out + (size_t)d * OUT_F))[l] = o;
}

extern "C" void kernel_launch(void* const* d_in, const int* in_sizes, int n_in,
                              void* d_out, int out_size, void* d_ws, size_t ws_size,
                              hipStream_t stream) {
  const float* feat = (const float*)d_in[0];
  const float* weight = (const float*)d_in[1];
  const float* bias = (const float*)d_in[2];
  const int* src = (const int*)d_in[3];
  const int* dst = (const int*)d_in[4];
  float* out = (float*)d_out;

  char* ws = (char*)d_ws;
  size_t off = 0;
  auto alloc = [&](size_t bytes) -> void* {
    void* p = ws + off;
    off += (bytes + 511) & ~(size_t)511;
    return p;
  };
  int* cnt = (int*)alloc(N_NODES * 4);
  int* row_off = (int*)alloc((N_NODES + 1) * 4);
  float* norm = (float*)alloc(N_NODES * 4);
  int* eidx = (int*)alloc(N_EDGES * 4);
  short* Wf = (short*)alloc(IN_F * OUT_F * 2);
  unsigned short* h = (unsigned short*)alloc((size_t)N_NODES * OUT_F * 2);
  int* blockSums = (int*)alloc(NGB * 4);
  unsigned short* pdst = (unsigned short*)alloc((size_t)CHUNKS * N_NODES * 2);
  unsigned short* psrc = (unsigned short*)alloc((size_t)CHUNKS * N_NODES * 2);
  unsigned short* delta = (unsigned short*)alloc((size_t)CHUNKS * N_NODES * 2);
  unsigned short* cnt_cg = (unsigned short*)alloc((size_t)CG * N_NODES * 2);
  unsigned short* rank16 = (unsigned short*)alloc((size_t)N_EDGES * 2);
  (void)off; (void)ws_size; (void)in_sizes; (void)n_in; (void)out_size;

  hipLaunchKernelGGL(hist_kernel, dim3(2 * CHUNKS * RANGES + 2), dim3(256), 0, stream,
                     src, dst, pdst, psrc, rank16, weight, Wf);
  hipLaunchKernelGGL(reduce_kernel, dim3(NGB, 2), dim3(256), 0, stream,
                     pdst, psrc, cnt, cnt_cg, blockSums, norm);
  hipLaunchKernelGGL(csr_kernel, dim3(NGB), dim3(256), 0, stream, cnt, blockSums, row_off);
  hipLaunchKernelGGL(offsets_kernel, dim3(NGB, CG), dim3(256), 0, stream, pdst, cnt_cg, delta);
  hipLaunchKernelGGL(scatter_kernel, dim3((N_EDGES / 4 + 255) / 256), dim3(256), 0, stream,
                     src, dst, row_off, delta, rank16, eidx);
  hipLaunchKernelGGL(gemm_kernel, dim3((N_NODES + 127) / 128), dim3(256), 0, stream, feat, Wf, norm, h);
  hipLaunchKernelGGL(agg_kernel, dim3(N_NODES / 4), dim3(256), 0, stream, h, row_off, eidx, bias, out);
}

// Round 6
// 207.154 us; speedup vs baseline: 1.1202x; 1.1202x over previous
//
#include <hip/hip_runtime.h>

#define N_NODES 50000
#define N_EDGES 800000
#define IN_F 256
#define OUT_F 128

#define CHUNKS 64
#define EPC (N_EDGES / CHUNKS)   // 12500 edges per chunk
#define RANGES 2
#define BPR 25000                // bins per range
#define BPRW (BPR / 2)           // packed u32 words (2 x u16 bins)
#define NGB 196                  // node-group blocks (256 nodes each)
#define HIST_BLOCKS (2 * CHUNKS * RANGES)  // 256

typedef __attribute__((ext_vector_type(8))) short short8;
typedef __attribute__((ext_vector_type(4))) float float4_t;

// float -> bf16 round-to-nearest-even
__device__ __forceinline__ short f2bf(float f) {
  unsigned u = __builtin_bit_cast(unsigned, f);
  u = u + 0x7FFFu + ((u >> 16) & 1u);
  return (short)(u >> 16);
}

__device__ __forceinline__ float bflo(unsigned u) {
  return __builtin_bit_cast(float, u << 16);
}
__device__ __forceinline__ float bfhi(unsigned u) {
  return __builtin_bit_cast(float, u & 0xFFFF0000u);
}

// ---- histogram + per-edge rank (LDS-privatized) + fused wprep ----
// blocks 0..255: b>>7 = side (0:dst, 1:src), (b>>1)&63 = chunk, b&1 = range
// blocks 256..257: W -> bf16 MFMA B-fragment layout
__global__ __launch_bounds__(256) void hist_kernel(const int* __restrict__ src,
                                                   const int* __restrict__ dst,
                                                   unsigned short* __restrict__ pdst,
                                                   unsigned short* __restrict__ psrc,
                                                   unsigned short* __restrict__ rank16,
                                                   const float* __restrict__ W,
                                                   short* __restrict__ Wf) {
  __shared__ unsigned bins[BPRW];
  int b = blockIdx.x;
  int t = threadIdx.x;
  if (b >= HIST_BLOCKS) {  // wprep: 2 blocks cover 32768 elements
    int bb = b - HIST_BLOCKS;
#pragma unroll
    for (int i = 0; i < 64; ++i) {
      int idx = bb * 16384 + i * 256 + t;
      int k = idx >> 7, n = idx & 127;
      int s = k >> 5, q = (k >> 3) & 3, j = k & 7;
      int tt = n >> 4, m = n & 15;
      Wf[(((s * 8 + tt) * 16 + m) * 32) + q * 8 + j] = f2bf(W[idx]);
    }
    return;
  }
  int h = b >> 7;
  int c = (b >> 1) & 63;
  int r = b & 1;
  int rbase = r * BPR;
  for (int j = t; j < BPRW; j += 256) bins[j] = 0;
  __syncthreads();
  const int* key = h ? src : dst;
  int e0 = c * EPC;

  auto process = [&](int v, int eI) {
    v -= rbase;
    if ((unsigned)v < (unsigned)BPR) {
      unsigned sh = (v & 1) * 16;
      unsigned old = atomicAdd(&bins[v >> 1], 1u << sh);
      if (!h) rank16[eI] = (unsigned short)((old >> sh) & 0xFFFFu);
    }
  };

  // 12 full tiles of 1024 + tail of 212 (EPC = 12500)
#pragma unroll 2
  for (int tile = 0; tile < 12; ++tile) {
    int i = tile * 1024 + t;
    int k0 = key[e0 + i];
    int k1 = key[e0 + i + 256];
    int k2 = key[e0 + i + 512];
    int k3 = key[e0 + i + 768];
    process(k0, e0 + i);
    process(k1, e0 + i + 256);
    process(k2, e0 + i + 512);
    process(k3, e0 + i + 768);
  }
  {
    int i = 12288 + t;
    if (i < EPC) process(key[e0 + i], e0 + i);
  }
  __syncthreads();
  unsigned* p32 = (unsigned*)((h ? psrc : pdst) + (size_t)c * N_NODES + rbase);
  for (int j = t; j < BPRW; j += 256) p32[j] = bins[j];
}

// grid (NGB, 2): side 0 -> delta (intra-node chunk prefix), cnt, blockSums; side 1 -> norm
__global__ __launch_bounds__(256) void reduceoff_kernel(const unsigned short* __restrict__ pdst,
                                                        const unsigned short* __restrict__ psrc,
                                                        unsigned short* __restrict__ delta,
                                                        int* __restrict__ cnt,
                                                        int* __restrict__ blockSums,
                                                        float* __restrict__ norm) {
  int g = blockIdx.x, side = blockIdx.y;
  int t = threadIdx.x;
  int v = g * 256 + t;
  bool ok = v < N_NODES;
  if (side == 0) {
    int run = 0;
#pragma unroll
    for (int c = 0; c < CHUNKS; ++c) {
      int d = ok ? (int)pdst[(size_t)c * N_NODES + v] : 0;
      if (ok) delta[(size_t)c * N_NODES + v] = (unsigned short)run;
      run += d;
    }
    if (ok) cnt[v] = run;
    int s = run;
    int l = t & 63, w = t >> 6;
    for (int off = 32; off > 0; off >>= 1) s += __shfl_down(s, off);
    __shared__ int wp[4];
    if (l == 0) wp[w] = s;
    __syncthreads();
    if (t == 0) blockSums[g] = wp[0] + wp[1] + wp[2] + wp[3];
  } else {
    int gsum = 0;
#pragma unroll
    for (int c = 0; c < CHUNKS; ++c)
      gsum += ok ? (int)psrc[(size_t)c * N_NODES + v] : 0;
    if (ok) norm[v] = 1.0f / (float)(gsum > 1 ? gsum : 1);
  }
}

// grid NGB: each block scans all block sums in LDS, then block-local scan of cnt -> row_off
__global__ __launch_bounds__(256) void csr_kernel(const int* __restrict__ cnt,
                                                  const int* __restrict__ blockSums,
                                                  int* __restrict__ row_off) {
  __shared__ int sc[256];
  int t = threadIdx.x, g = blockIdx.x;
  sc[t] = (t < NGB) ? blockSums[t] : 0;
  __syncthreads();
  for (int off = 1; off < 256; off <<= 1) {
    int nv = (t >= off) ? sc[t - off] : 0;
    __syncthreads();
    sc[t] += nv;
    __syncthreads();
  }
  int myBase = sc[g] - blockSums[g];  // exclusive prefix for this block
  int v = g * 256 + t;
  int cv = (v < N_NODES) ? cnt[v] : 0;
  int l = t & 63, w = t >> 6;
  int x = cv;
  for (int off = 1; off < 64; off <<= 1) {
    int y = __shfl_up(x, off);
    if (l >= off) x += y;
  }
  __shared__ int wp[4];
  if (l == 63) wp[w] = x;
  __syncthreads();
  int add = 0;
  for (int i = 0; i < w; ++i) add += wp[i];
  int P = myBase + add + x - cv;  // exclusive global prefix
  if (v < N_NODES) {
    row_off[v] = P;
    if (v == N_NODES - 1) row_off[N_NODES] = P + cv;
  }
}

// stateless streaming scatter: pos = row_off[dst] + delta[chunk][dst] + rank16[e]
__global__ __launch_bounds__(256) void scatter_kernel(const int* __restrict__ src,
                                                      const int* __restrict__ dst,
                                                      const int* __restrict__ row_off,
                                                      const unsigned short* __restrict__ delta,
                                                      const unsigned short* __restrict__ rank16,
                                                      int* __restrict__ eidx) {
  int tid = blockIdx.x * 256 + threadIdx.x;
  int e = tid * 4;
  if (e >= N_EDGES) return;
  int4 d4 = *(const int4*)(dst + e);
  int4 s4 = *(const int4*)(src + e);
  uint2 rr = *(const uint2*)(rank16 + e);
  int c = e / EPC;  // EPC % 4 == 0: the 4-edge group never straddles a chunk
  const unsigned short* drow = delta + (size_t)c * N_NODES;
  int dd[4] = {d4.x, d4.y, d4.z, d4.w};
  int ss[4] = {s4.x, s4.y, s4.z, s4.w};
  unsigned rk[4] = {rr.x & 0xFFFFu, rr.x >> 16, rr.y & 0xFFFFu, rr.y >> 16};
#pragma unroll
  for (int k = 0; k < 4; ++k) {
    int d = dd[k];
    int pos = row_off[d] + (int)drow[d] + (int)rk[k];
    eidx[pos] = ss[k];
  }
}

// h = (feat @ W) * norm[row], stored as bf16. No LDS.
// Block: 128 thr = 2 waves; wave handles 32 rows x 128 cols. Grid 782 (~3 blocks/CU).
__global__ __launch_bounds__(128) void gemm_kernel(const float* __restrict__ feat,
                                                   const short* __restrict__ Wf,
                                                   const float* __restrict__ norm,
                                                   unsigned short* __restrict__ h) {
  int tid = threadIdx.x;
  int w = tid >> 6, l = tid & 63;
  int m = l & 15, q = l >> 4;
  long base = (long)blockIdx.x * 64 + w * 32;

  float4_t acc[2][8];
#pragma unroll
  for (int r = 0; r < 2; ++r)
#pragma unroll
    for (int t = 0; t < 8; ++t) acc[r][t] = (float4_t)(0.0f);

  long row0 = base + m;
  long row1 = base + 16 + m;
  long r0c = row0 < N_NODES - 1 ? row0 : N_NODES - 1;
  long r1c = row1 < N_NODES - 1 ? row1 : N_NODES - 1;
  const float* a0p = feat + (size_t)r0c * IN_F;
  const float* a1p = feat + (size_t)r1c * IN_F;
  const short8* bb = (const short8*)Wf;

#pragma unroll
  for (int s = 0; s < 8; ++s) {
    int k0 = s * 32 + q * 8;
    float4_t av0a = *(const float4_t*)(a0p + k0);
    float4_t av0b = *(const float4_t*)(a0p + k0 + 4);
    float4_t av1a = *(const float4_t*)(a1p + k0);
    float4_t av1b = *(const float4_t*)(a1p + k0 + 4);
    short8 fa0, fa1;
#pragma unroll
    for (int i = 0; i < 4; ++i) {
      fa0[i] = f2bf(av0a[i]);
      fa0[i + 4] = f2bf(av0b[i]);
      fa1[i] = f2bf(av1a[i]);
      fa1[i + 4] = f2bf(av1b[i]);
    }
#pragma unroll
    for (int t = 0; t < 8; ++t) {
      short8 fb = bb[((s * 8 + t) * 16 + m) * 4 + q];
      acc[0][t] = __builtin_amdgcn_mfma_f32_16x16x32_bf16(fa0, fb, acc[0][t], 0, 0, 0);
      acc[1][t] = __builtin_amdgcn_mfma_f32_16x16x32_bf16(fa1, fb, acc[1][t], 0, 0, 0);
    }
  }

  // C/D layout: col = lane&15 (=m), row = q*4 + i
#pragma unroll
  for (int r = 0; r < 2; ++r) {
#pragma unroll
    for (int i = 0; i < 4; ++i) {
      long row = base + r * 16 + q * 4 + i;
      if (row < N_NODES) {
        float nm = norm[row];
        size_t ho = (size_t)row * OUT_F;
#pragma unroll
        for (int t = 0; t < 8; ++t) {
          h[ho + t * 16 + m] = (unsigned short)f2bf(acc[r][t][i] * nm);
        }
      }
    }
  }
}

// One wave per dst node; wave processes 2 h-rows/step (32 lanes x 8 B each).
__global__ __launch_bounds__(256) void agg_kernel(const unsigned short* __restrict__ h,
                                                  const int* __restrict__ row_off,
                                                  const int* __restrict__ eidx,
                                                  const float* __restrict__ bias,
                                                  float* __restrict__ out) {
  int w = threadIdx.x >> 6, l = threadIdx.x & 63;
  int d = blockIdx.x * 4 + w;  // grid 12500 -> exactly 50000
  int rs = row_off[d], re = row_off[d + 1];
  const unsigned* __restrict__ hu = (const unsigned*)h;  // 64 uints per row
  int rowsel = l >> 5, cp = l & 31;  // lane covers cols 4*cp .. 4*cp+3
  float a0 = 0.f, a1 = 0.f, a2 = 0.f, a3 = 0.f;
  for (int bse = rs; bse < re; bse += 64) {
    int n = re - bse; if (n > 64) n = 64;
    int e = (l < n) ? eidx[bse + l] : 0;
    int half = (n + 1) >> 1;
    int j = 0;
    for (; j + 2 <= half; j += 2) {
      int i0 = 2 * j + rowsel;
      int i1 = i0 + 2;
      int s0 = __shfl(e, i0);
      int s1 = __shfl(e, i1);
      uint2 v0 = *(const uint2*)(hu + (size_t)s0 * 64 + 2 * cp);
      uint2 v1 = *(const uint2*)(hu + (size_t)s1 * 64 + 2 * cp);
      if (i0 >= n) { v0.x = 0; v0.y = 0; }
      if (i1 >= n) { v1.x = 0; v1.y = 0; }
      a0 += bflo(v0.x); a1 += bfhi(v0.x); a2 += bflo(v0.y); a3 += bfhi(v0.y);
      a0 += bflo(v1.x); a1 += bfhi(v1.x); a2 += bflo(v1.y); a3 += bfhi(v1.y);
    }
    for (; j < half; ++j) {
      int i0 = 2 * j + rowsel;
      int s0 = __shfl(e, i0);
      uint2 v0 = *(const uint2*)(hu + (size_t)s0 * 64 + 2 * cp);
      if (i0 >= n) { v0.x = 0; v0.y = 0; }
      a0 += bflo(v0.x); a1 += bfhi(v0.x); a2 += bflo(v0.y); a3 += bfhi(v0.y);
    }
  }
  a0 += __shfl_xor(a0, 32);
  a1 += __shfl_xor(a1, 32);
  a2 += __shfl_xor(a2, 32);
  a3 += __shfl_xor(a3, 32);
  if (rowsel == 0) {
    float4 bv = ((const float4*)bias)[cp];
    float4 o;
    o.x = a0 + bv.x; o.y = a1 + bv.y; o.z = a2 + bv.z; o.w = a3 + bv.w;
    ((float4*)(out + (size_t)d * OUT_F))[cp] = o;
  }
}

extern "C" void kernel_launch(void* const* d_in, const int* in_sizes, int n_in,
                              void* d_out, int out_size, void* d_ws, size_t ws_size,
                              hipStream_t stream) {
  const float* feat = (const float*)d_in[0];
  const float* weight = (const float*)d_in[1];
  const float* bias = (const float*)d_in[2];
  const int* src = (const int*)d_in[3];
  const int* dst = (const int*)d_in[4];
  float* out = (float*)d_out;

  char* ws = (char*)d_ws;
  size_t off = 0;
  auto alloc = [&](size_t bytes) -> void* {
    void* p = ws + off;
    off += (bytes + 511) & ~(size_t)511;
    return p;
  };
  int* cnt = (int*)alloc(N_NODES * 4);
  int* row_off = (int*)alloc((N_NODES + 1) * 4);
  float* norm = (float*)alloc(N_NODES * 4);
  int* eidx = (int*)alloc(N_EDGES * 4);
  short* Wf = (short*)alloc(IN_F * OUT_F * 2);
  unsigned short* h = (unsigned short*)alloc((size_t)N_NODES * OUT_F * 2);
  int* blockSums = (int*)alloc(NGB * 4);
  unsigned short* pdst = (unsigned short*)alloc((size_t)CHUNKS * N_NODES * 2);
  unsigned short* psrc = (unsigned short*)alloc((size_t)CHUNKS * N_NODES * 2);
  unsigned short* delta = (unsigned short*)alloc((size_t)CHUNKS * N_NODES * 2);
  unsigned short* rank16 = (unsigned short*)alloc((size_t)N_EDGES * 2);
  (void)off; (void)ws_size; (void)in_sizes; (void)n_in; (void)out_size;

  hipLaunchKernelGGL(hist_kernel, dim3(HIST_BLOCKS + 2), dim3(256), 0, stream,
                     src, dst, pdst, psrc, rank16, weight, Wf);
  hipLaunchKernelGGL(reduceoff_kernel, dim3(NGB, 2), dim3(256), 0, stream,
                     pdst, psrc, delta, cnt, blockSums, norm);
  hipLaunchKernelGGL(csr_kernel, dim3(NGB), dim3(256), 0, stream, cnt, blockSums, row_off);
  hipLaunchKernelGGL(scatter_kernel, dim3((N_EDGES / 4 + 255) / 256), dim3(256), 0, stream,
                     src, dst, row_off, delta, rank16, eidx);
  hipLaunchKernelGGL(gemm_kernel, dim3((N_NODES + 63) / 64), dim3(128), 0, stream, feat, Wf, norm, h);
  hipLaunchKernelGGL(agg_kernel, dim3(N_NODES / 4), dim3(256), 0, stream, h, row_off, eidx, bias, out);
}